// Round 1
// baseline (415.122 us; speedup 1.0000x reference)
//
#include <hip/hip_runtime.h>
#include <stdint.h>

// Problem constants (B=8, T=2048, D=256, K=8192)
#define M_TOK 16384
#define DIM   256
#define KCB   8192
#define NSPLIT 64                  // KCB / 128
#define INV_N (1.0f / 4194304.0f)  // 1/(B*T*D)

typedef __attribute__((ext_vector_type(4))) float f32x4;
typedef __attribute__((ext_vector_type(8))) __bf16 bf16x8;

static __device__ __forceinline__ unsigned short f2bf(float f) {
    uint32_t x = __float_as_uint(f);
    uint32_t r = (x + 0x7fffu + ((x >> 16) & 1u)) >> 16;   // RNE
    return (unsigned short)r;
}

// ---------------------------------------------------------------- kernel 1
// xs fp32 -> bf16 (row-major [16384][256]); also zero the loss accumulator.
__global__ void k_conv_xs(const float4* __restrict__ xs4,
                          ushort4* __restrict__ xb4,
                          float* __restrict__ acc) {
    int i = blockIdx.x * 256 + threadIdx.x;          // exactly M_TOK*DIM/4 threads
    if (i == 0) *acc = 0.0f;
    float4 v = xs4[i];
    ushort4 o;
    o.x = f2bf(v.x); o.y = f2bf(v.y); o.z = f2bf(v.z); o.w = f2bf(v.w);
    xb4[i] = o;
}

// ---------------------------------------------------------------- kernel 2
// codebook fp32 -> bf16; c_half_sq[k] = 0.5*||c_k||^2 (fp32). One wave per row.
__global__ void k_conv_cb(const float4* __restrict__ cb4,
                          ushort4* __restrict__ cbb4,
                          float* __restrict__ chalf) {
    int row  = blockIdx.x * 4 + (threadIdx.x >> 6);
    int lane = threadIdx.x & 63;
    int idx  = row * 64 + lane;                      // float4 units (256 floats/row)
    float4 v = cb4[idx];
    ushort4 o;
    o.x = f2bf(v.x); o.y = f2bf(v.y); o.z = f2bf(v.z); o.w = f2bf(v.w);
    cbb4[idx] = o;
    float s = v.x * v.x + v.y * v.y + v.z * v.z + v.w * v.w;
    #pragma unroll
    for (int off = 32; off; off >>= 1) s += __shfl_xor(s, off);
    if (lane == 0) chalf[row] = 0.5f * s;
}

// ---------------------------------------------------------------- kernel 3
// 128x128-tile bf16 MFMA GEMM with fused argmin epilogue.
// grid = (M_TOK/128, KCB/128); block = 256 threads = 4 waves, each wave a
// 64x64 quadrant (4x4 tiles of 16x16x32 MFMA). score = 0.5||c||^2 - x.c
// (monotone in squared distance for a fixed row). Partials per (row, nsplit).
__global__ __launch_bounds__(256, 2) void k_gemm_argmin(
    const unsigned short* __restrict__ xb,    // [M_TOK][DIM] bf16 bits
    const unsigned short* __restrict__ cbb,   // [KCB][DIM]  bf16 bits
    const float* __restrict__ chalf,          // [KCB]
    float* __restrict__ pval,                 // [M_TOK][NSPLIT]
    int* __restrict__ pidx)                   // [M_TOK][NSPLIT]
{
    __shared__ __align__(16) unsigned short As[128][40];  // 32 + 8 pad (bank-spread)
    __shared__ __align__(16) unsigned short Bs[128][40];
    __shared__ float sv[128][2];
    __shared__ int   si[128][2];

    const int tid   = threadIdx.x;
    const int w     = tid >> 6;       // wave 0..3
    const int l     = tid & 63;
    const int lrow  = l & 15;         // n (col) index inside 16x16 tile
    const int lquad = l >> 4;         // 0..3
    const int m0 = blockIdx.x * 128;
    const int n0 = blockIdx.y * 128;
    const int wm = (w >> 1) * 64;     // wave row offset in tile
    const int wn = (w & 1) * 64;      // wave col offset in tile

    const int srow = tid >> 2;        // staging: row 0..63
    const int sseg = (tid & 3) * 8;   // staging: 8-elem (16B) segment

    f32x4 acc[4][4] = {};

    for (int kk = 0; kk < DIM; kk += 32) {
        uint4 a0 = *(const uint4*)(xb  + (size_t)(m0 + srow)      * DIM + kk + sseg);
        uint4 a1 = *(const uint4*)(xb  + (size_t)(m0 + srow + 64) * DIM + kk + sseg);
        uint4 b0 = *(const uint4*)(cbb + (size_t)(n0 + srow)      * DIM + kk + sseg);
        uint4 b1 = *(const uint4*)(cbb + (size_t)(n0 + srow + 64) * DIM + kk + sseg);
        *(uint4*)&As[srow][sseg]      = a0;
        *(uint4*)&As[srow + 64][sseg] = a1;
        *(uint4*)&Bs[srow][sseg]      = b0;
        *(uint4*)&Bs[srow + 64][sseg] = b1;
        __syncthreads();

        bf16x8 afr[4], bfr[4];
        #pragma unroll
        for (int rt = 0; rt < 4; rt++)
            afr[rt] = *(const bf16x8*)&As[wm + rt * 16 + lrow][lquad * 8];
        #pragma unroll
        for (int ct = 0; ct < 4; ct++)
            bfr[ct] = *(const bf16x8*)&Bs[wn + ct * 16 + lrow][lquad * 8];
        #pragma unroll
        for (int rt = 0; rt < 4; rt++)
            #pragma unroll
            for (int ct = 0; ct < 4; ct++)
                acc[rt][ct] = __builtin_amdgcn_mfma_f32_16x16x32_bf16(
                    afr[rt], bfr[ct], acc[rt][ct], 0, 0, 0);
        __syncthreads();
    }

    // ---- epilogue: per-lane argmin over its 4 cols, then lane/wave reduce
    float bv[4][4];
    int   bi[4][4];
    #pragma unroll
    for (int rt = 0; rt < 4; rt++)
        #pragma unroll
        for (int rg = 0; rg < 4; rg++) { bv[rt][rg] = 3.4e38f; bi[rt][rg] = 0; }

    #pragma unroll
    for (int ct = 0; ct < 4; ct++) {
        int code = n0 + wn + ct * 16 + lrow;
        float cs = chalf[code];
        #pragma unroll
        for (int rt = 0; rt < 4; rt++)
            #pragma unroll
            for (int rg = 0; rg < 4; rg++) {
                float s = cs - acc[rt][ct][rg];
                if (s < bv[rt][rg]) { bv[rt][rg] = s; bi[rt][rg] = code; }
            }
    }
    // reduce across the 16 lanes of a quad group (same rows, different cols)
    #pragma unroll
    for (int off = 1; off < 16; off <<= 1) {
        #pragma unroll
        for (int rt = 0; rt < 4; rt++)
            #pragma unroll
            for (int rg = 0; rg < 4; rg++) {
                float ov = __shfl_xor(bv[rt][rg], off);
                int   oi = __shfl_xor(bi[rt][rg], off);
                if (ov < bv[rt][rg] || (ov == bv[rt][rg] && oi < bi[rt][rg])) {
                    bv[rt][rg] = ov; bi[rt][rg] = oi;
                }
            }
    }
    if (lrow == 0) {
        #pragma unroll
        for (int rt = 0; rt < 4; rt++)
            #pragma unroll
            for (int rg = 0; rg < 4; rg++) {
                int rloc = wm + rt * 16 + lquad * 4 + rg;
                sv[rloc][w & 1] = bv[rt][rg];
                si[rloc][w & 1] = bi[rt][rg];
            }
    }
    __syncthreads();
    if (tid < 128) {
        float v0 = sv[tid][0], v1 = sv[tid][1];
        int   i0 = si[tid][0], i1 = si[tid][1];
        bool take1 = (v1 < v0) || (v1 == v0 && i1 < i0);
        float v = take1 ? v1 : v0;
        int   ix = take1 ? i1 : i0;
        size_t grow = (size_t)(m0 + tid);
        pval[grow * NSPLIT + blockIdx.y] = v;
        pidx[grow * NSPLIT + blockIdx.y] = ix;
    }
}

// ---------------------------------------------------------------- kernel 4
// Per row: min over 64 split partials -> final index; exact fp32 distance;
// block-level atomicAdd into the accumulator. One wave per row.
__global__ void k_finalize(const float* __restrict__ pval,
                           const int* __restrict__ pidx,
                           const float4* __restrict__ xs4,
                           const float4* __restrict__ cb4,
                           float* __restrict__ acc) {
    int row = blockIdx.x * 4 + (threadIdx.x >> 6);
    int l   = threadIdx.x & 63;
    float v = pval[(size_t)row * NSPLIT + l];
    int  ix = pidx[(size_t)row * NSPLIT + l];
    #pragma unroll
    for (int off = 1; off < 64; off <<= 1) {
        float ov = __shfl_xor(v, off);
        int   oi = __shfl_xor(ix, off);
        if (ov < v || (ov == v && oi < ix)) { v = ov; ix = oi; }
    }
    float4 x = xs4[(size_t)row * 64 + l];
    float4 c = cb4[(size_t)ix * 64 + l];
    float dx = x.x - c.x, dy = x.y - c.y, dz = x.z - c.z, dw = x.w - c.w;
    float s = dx * dx + dy * dy + dz * dz + dw * dw;
    #pragma unroll
    for (int off = 32; off; off >>= 1) s += __shfl_xor(s, off);
    if (l == 0) atomicAdd(acc, s);
}

// ---------------------------------------------------------------- kernel 5
__global__ void k_write(const float* __restrict__ acc, float* __restrict__ out) {
    if (threadIdx.x == 0) {
        float commit = *acc * INV_N;
        out[0] = 0.25f * commit;   // loss
        out[1] = commit;           // commit_loss
    }
}

extern "C" void kernel_launch(void* const* d_in, const int* in_sizes, int n_in,
                              void* d_out, int out_size, void* d_ws, size_t ws_size,
                              hipStream_t stream) {
    const float* xs = (const float*)d_in[0];
    // d_in[1] = ilens (int64, all == T) -> slice is a no-op, unused
    const float* cb = (const float*)d_in[2];

    char* ws = (char*)d_ws;
    float*          acc   = (float*)ws;                               // 4 B
    unsigned short* xb    = (unsigned short*)(ws + 256);              // 8 MiB
    unsigned short* cbb   = (unsigned short*)(ws + 256 + 8388608);    // 4 MiB
    float*          chalf = (float*)(ws + 256 + 12582912);            // 32 KiB
    float*          pval  = (float*)(ws + 256 + 12615680);            // 4 MiB
    int*            pidx  = (int*)  (ws + 256 + 16809984);            // 4 MiB

    k_conv_xs<<<4096, 256, 0, stream>>>((const float4*)xs, (ushort4*)xb, acc);
    k_conv_cb<<<2048, 256, 0, stream>>>((const float4*)cb, (ushort4*)cbb, chalf);
    dim3 g(M_TOK / 128, KCB / 128);
    k_gemm_argmin<<<g, 256, 0, stream>>>(xb, cbb, chalf, pval, pidx);
    k_finalize<<<4096, 256, 0, stream>>>(pval, pidx, (const float4*)xs,
                                         (const float4*)cb, acc);
    k_write<<<1, 64, 0, stream>>>(acc, (float*)d_out);
}

// Round 2
// 208.409 us; speedup vs baseline: 1.9919x; 1.9919x over previous
//
#include <hip/hip_runtime.h>
#include <stdint.h>

// Problem constants (B=8, T=2048, D=256, K=8192)
#define M_TOK 16384
#define DIM   256
#define KCB   8192
#define NSPLIT 64                  // KCB / 128
#define INV_N (1.0f / 4194304.0f)  // 1/(B*T*D)

typedef __attribute__((ext_vector_type(4))) float f32x4;
typedef __attribute__((ext_vector_type(8))) __bf16 bf16x8;

static __device__ __forceinline__ unsigned short f2bf(float f) {
    uint32_t x = __float_as_uint(f);
    uint32_t r = (x + 0x7fffu + ((x >> 16) & 1u)) >> 16;   // RNE
    return (unsigned short)r;
}

// ---------------------------------------------------------------- kernel 1
// xs fp32 -> bf16 (row-major [16384][256]).
__global__ void k_conv_xs(const float4* __restrict__ xs4,
                          ushort4* __restrict__ xb4) {
    int i = blockIdx.x * 256 + threadIdx.x;          // exactly M_TOK*DIM/4 threads
    float4 v = xs4[i];
    ushort4 o;
    o.x = f2bf(v.x); o.y = f2bf(v.y); o.z = f2bf(v.z); o.w = f2bf(v.w);
    xb4[i] = o;
}

// ---------------------------------------------------------------- kernel 2
// codebook fp32 -> bf16; c_half_sq[k] = 0.5*||c_k||^2 (fp32). One wave per row.
__global__ void k_conv_cb(const float4* __restrict__ cb4,
                          ushort4* __restrict__ cbb4,
                          float* __restrict__ chalf) {
    int row  = blockIdx.x * 4 + (threadIdx.x >> 6);
    int lane = threadIdx.x & 63;
    int idx  = row * 64 + lane;                      // float4 units (256 floats/row)
    float4 v = cb4[idx];
    ushort4 o;
    o.x = f2bf(v.x); o.y = f2bf(v.y); o.z = f2bf(v.z); o.w = f2bf(v.w);
    cbb4[idx] = o;
    float s = v.x * v.x + v.y * v.y + v.z * v.z + v.w * v.w;
    #pragma unroll
    for (int off = 32; off; off >>= 1) s += __shfl_xor(s, off);
    if (lane == 0) chalf[row] = 0.5f * s;
}

// ---------------------------------------------------------------- kernel 3
// 128x128-tile bf16 MFMA GEMM with fused argmin epilogue.
// grid = (M_TOK/128, KCB/128); block = 256 threads = 4 waves, each wave a
// 64x64 quadrant (4x4 tiles of 16x16x32 MFMA). score = 0.5||c||^2 - x.c
// (monotone in squared distance for a fixed row). Partials per (row, nsplit).
__global__ __launch_bounds__(256, 2) void k_gemm_argmin(
    const unsigned short* __restrict__ xb,    // [M_TOK][DIM] bf16 bits
    const unsigned short* __restrict__ cbb,   // [KCB][DIM]  bf16 bits
    const float* __restrict__ chalf,          // [KCB]
    float* __restrict__ pval,                 // [M_TOK][NSPLIT]
    int* __restrict__ pidx)                   // [M_TOK][NSPLIT]
{
    __shared__ __align__(16) unsigned short As[128][40];  // 32 + 8 pad (bank-spread)
    __shared__ __align__(16) unsigned short Bs[128][40];
    __shared__ float sv[128][2];
    __shared__ int   si[128][2];

    const int tid   = threadIdx.x;
    const int w     = tid >> 6;       // wave 0..3
    const int l     = tid & 63;
    const int lrow  = l & 15;         // n (col) index inside 16x16 tile
    const int lquad = l >> 4;         // 0..3
    const int m0 = blockIdx.x * 128;
    const int n0 = blockIdx.y * 128;
    const int wm = (w >> 1) * 64;     // wave row offset in tile
    const int wn = (w & 1) * 64;      // wave col offset in tile

    const int srow = tid >> 2;        // staging: row 0..63
    const int sseg = (tid & 3) * 8;   // staging: 8-elem (16B) segment

    f32x4 acc[4][4] = {};

    for (int kk = 0; kk < DIM; kk += 32) {
        uint4 a0 = *(const uint4*)(xb  + (size_t)(m0 + srow)      * DIM + kk + sseg);
        uint4 a1 = *(const uint4*)(xb  + (size_t)(m0 + srow + 64) * DIM + kk + sseg);
        uint4 b0 = *(const uint4*)(cbb + (size_t)(n0 + srow)      * DIM + kk + sseg);
        uint4 b1 = *(const uint4*)(cbb + (size_t)(n0 + srow + 64) * DIM + kk + sseg);
        *(uint4*)&As[srow][sseg]      = a0;
        *(uint4*)&As[srow + 64][sseg] = a1;
        *(uint4*)&Bs[srow][sseg]      = b0;
        *(uint4*)&Bs[srow + 64][sseg] = b1;
        __syncthreads();

        bf16x8 afr[4], bfr[4];
        #pragma unroll
        for (int rt = 0; rt < 4; rt++)
            afr[rt] = *(const bf16x8*)&As[wm + rt * 16 + lrow][lquad * 8];
        #pragma unroll
        for (int ct = 0; ct < 4; ct++)
            bfr[ct] = *(const bf16x8*)&Bs[wn + ct * 16 + lrow][lquad * 8];
        #pragma unroll
        for (int rt = 0; rt < 4; rt++)
            #pragma unroll
            for (int ct = 0; ct < 4; ct++)
                acc[rt][ct] = __builtin_amdgcn_mfma_f32_16x16x32_bf16(
                    afr[rt], bfr[ct], acc[rt][ct], 0, 0, 0);
        __syncthreads();
    }

    // ---- epilogue: per-lane argmin over its 4 cols, then lane/wave reduce
    float bv[4][4];
    int   bi[4][4];
    #pragma unroll
    for (int rt = 0; rt < 4; rt++)
        #pragma unroll
        for (int rg = 0; rg < 4; rg++) { bv[rt][rg] = 3.4e38f; bi[rt][rg] = 0; }

    #pragma unroll
    for (int ct = 0; ct < 4; ct++) {
        int code = n0 + wn + ct * 16 + lrow;
        float cs = chalf[code];
        #pragma unroll
        for (int rt = 0; rt < 4; rt++)
            #pragma unroll
            for (int rg = 0; rg < 4; rg++) {
                float s = cs - acc[rt][ct][rg];
                if (s < bv[rt][rg]) { bv[rt][rg] = s; bi[rt][rg] = code; }
            }
    }
    // reduce across the 16 lanes of a quad group (same rows, different cols)
    #pragma unroll
    for (int off = 1; off < 16; off <<= 1) {
        #pragma unroll
        for (int rt = 0; rt < 4; rt++)
            #pragma unroll
            for (int rg = 0; rg < 4; rg++) {
                float ov = __shfl_xor(bv[rt][rg], off);
                int   oi = __shfl_xor(bi[rt][rg], off);
                if (ov < bv[rt][rg] || (ov == bv[rt][rg] && oi < bi[rt][rg])) {
                    bv[rt][rg] = ov; bi[rt][rg] = oi;
                }
            }
    }
    if (lrow == 0) {
        #pragma unroll
        for (int rt = 0; rt < 4; rt++)
            #pragma unroll
            for (int rg = 0; rg < 4; rg++) {
                int rloc = wm + rt * 16 + lquad * 4 + rg;
                sv[rloc][w & 1] = bv[rt][rg];
                si[rloc][w & 1] = bi[rt][rg];
            }
    }
    __syncthreads();
    if (tid < 128) {
        float v0 = sv[tid][0], v1 = sv[tid][1];
        int   i0 = si[tid][0], i1 = si[tid][1];
        bool take1 = (v1 < v0) || (v1 == v0 && i1 < i0);
        float v = take1 ? v1 : v0;
        int   ix = take1 ? i1 : i0;
        size_t grow = (size_t)(m0 + tid);
        pval[grow * NSPLIT + blockIdx.y] = v;
        pidx[grow * NSPLIT + blockIdx.y] = ix;
    }
}

// ---------------------------------------------------------------- kernel 4
// Per row: min over 64 split partials -> final index; exact fp32 distance;
// per-block LDS reduce -> partial[blockIdx]. NO global atomics (round-1
// post-mortem: 16384 same-address atomicAdds serialized -> 211 us).
__global__ void k_finalize(const float* __restrict__ pval,
                           const int* __restrict__ pidx,
                           const float4* __restrict__ xs4,
                           const float4* __restrict__ cb4,
                           float* __restrict__ partial) {
    __shared__ float sblk[4];
    int w   = threadIdx.x >> 6;
    int row = blockIdx.x * 4 + w;
    int l   = threadIdx.x & 63;
    float v = pval[(size_t)row * NSPLIT + l];
    int  ix = pidx[(size_t)row * NSPLIT + l];
    #pragma unroll
    for (int off = 1; off < 64; off <<= 1) {
        float ov = __shfl_xor(v, off);
        int   oi = __shfl_xor(ix, off);
        if (ov < v || (ov == v && oi < ix)) { v = ov; ix = oi; }
    }
    float4 x = xs4[(size_t)row * 64 + l];
    float4 c = cb4[(size_t)ix * 64 + l];
    float dx = x.x - c.x, dy = x.y - c.y, dz = x.z - c.z, dw = x.w - c.w;
    float s = dx * dx + dy * dy + dz * dz + dw * dw;
    #pragma unroll
    for (int off = 32; off; off >>= 1) s += __shfl_xor(s, off);
    if (l == 0) sblk[w] = s;
    __syncthreads();
    if (threadIdx.x == 0)
        partial[blockIdx.x] = sblk[0] + sblk[1] + sblk[2] + sblk[3];
}

// ---------------------------------------------------------------- kernel 5
// Single block reduces 4096 block-partials and writes the two scalars.
__global__ void k_write(const float* __restrict__ partial,
                        float* __restrict__ out) {
    __shared__ float swv[16];
    int tid = threadIdx.x;                    // 1024 threads = 16 waves
    float s = partial[tid] + partial[tid + 1024] +
              partial[tid + 2048] + partial[tid + 3072];
    #pragma unroll
    for (int off = 32; off; off >>= 1) s += __shfl_xor(s, off);
    if ((tid & 63) == 0) swv[tid >> 6] = s;
    __syncthreads();
    if (tid == 0) {
        float t = 0.0f;
        #pragma unroll
        for (int i = 0; i < 16; i++) t += swv[i];
        float commit = t * INV_N;
        out[0] = 0.25f * commit;   // loss
        out[1] = commit;           // commit_loss
    }
}

extern "C" void kernel_launch(void* const* d_in, const int* in_sizes, int n_in,
                              void* d_out, int out_size, void* d_ws, size_t ws_size,
                              hipStream_t stream) {
    const float* xs = (const float*)d_in[0];
    // d_in[1] = ilens (int64, all == T) -> slice is a no-op, unused
    const float* cb = (const float*)d_in[2];

    char* ws = (char*)d_ws;
    unsigned short* xb      = (unsigned short*)(ws + 256);              // 8 MiB
    unsigned short* cbb     = (unsigned short*)(ws + 256 + 8388608);    // 4 MiB
    float*          chalf   = (float*)(ws + 256 + 12582912);            // 32 KiB
    float*          pval    = (float*)(ws + 256 + 12615680);            // 4 MiB
    int*            pidx    = (int*)  (ws + 256 + 16809984);            // 4 MiB
    float*          partial = (float*)(ws + 256 + 21004288);            // 16 KiB

    k_conv_xs<<<4096, 256, 0, stream>>>((const float4*)xs, (ushort4*)xb);
    k_conv_cb<<<2048, 256, 0, stream>>>((const float4*)cb, (ushort4*)cbb, chalf);
    dim3 g(M_TOK / 128, KCB / 128);
    k_gemm_argmin<<<g, 256, 0, stream>>>(xb, cbb, chalf, pval, pidx);
    k_finalize<<<4096, 256, 0, stream>>>(pval, pidx, (const float4*)xs,
                                         (const float4*)cb, partial);
    k_write<<<1, 1024, 0, stream>>>(partial, (float*)d_out);
}